// Round 16
// baseline (142.860 us; speedup 1.0000x reference)
//
#include <hip/hip_runtime.h>
#include <stdint.h>

// MultiHeadAttentionLayer: bf16-MFMA pipeline, f32 output.
// Best-known config (r13/r14) + proj upgraded to the r12-verified counted-vmcnt
// triple-buffer protocol (loads stay in flight across barriers; no vmcnt(0)
// drain in the main loop). attn/out/prep byte-identical to round 14.
//   prep_weights: Wq/Wk/Wv ([H,D,E] f32) -> W^T bf16 [H*E][D]; Wo -> Wo^T bf16
//   proj_gemm:    128x128, BK=32; A staged f32 via global_load_lds (3 bufs),
//                 f32->bf16 fused into fragment read (cvt_pk); vmcnt(6)+s_barrier.
//   attn_kernel:  swapped QK^T, static-max, 32 q/wave, dbuf 128-kv tiles.
//   out_gemm:     double-buffered; att[4096x1024] @ Wo^T + bo -> d_out (f32). T1.

typedef __attribute__((ext_vector_type(8))) short bf16x8;
typedef __attribute__((ext_vector_type(4))) float f32x4;

#define DEVFN static __device__ __forceinline__

static constexpr int S_ = 2048;
static constexpr int H_ = 16;

DEVFN unsigned short f2bf(float x) {
  union { float f; uint32_t u; } v; v.f = x;
  const uint32_t r = v.u + 0x7fffu + ((v.u >> 16) & 1u);  // RNE
  return (unsigned short)(r >> 16);
}

DEVFN f32x4 fzero() { f32x4 v = {0.f, 0.f, 0.f, 0.f}; return v; }

union U8 { uint32_t u[4]; bf16x8 v; };

// global -> LDS direct copy, 16B per lane; LDS dest must be wave-uniform base.
DEVFN void gld_lds16(const void* g, void* lds) {
  __builtin_amdgcn_global_load_lds(
      (const __attribute__((address_space(1))) void*)g,
      (__attribute__((address_space(3))) void*)lds, 16, 0, 0);
}

// ---------------------------------------------------------------------------
// Weight prep: dst[c][d] = W[h=c>>6][d][e=c&63] (z<3) or Wo[d][c] (z==3), bf16
// ---------------------------------------------------------------------------
__global__ void prep_weights(const float* __restrict__ Wq, const float* __restrict__ Wk,
                             const float* __restrict__ Wv, const float* __restrict__ Wo,
                             unsigned short* __restrict__ dstBase) {
  const int z = blockIdx.z;
  const float* src = (z == 0) ? Wq : (z == 1) ? Wk : (z == 2) ? Wv : Wo;
  unsigned short* dst = dstBase + (size_t)z * (1024u * 1024u);
  const int idx = blockIdx.x * 256 + threadIdx.x;  // 131072 threads
  const int c = idx & 1023;
  const int d0 = (idx >> 10) << 3;
  unsigned short hv[8];
#pragma unroll
  for (int t = 0; t < 8; ++t) {
    const int d = d0 + t;
    const float v = (z < 3) ? src[(size_t)((c >> 6) * 1024 + d) * 64 + (c & 63)]
                            : src[(size_t)d * 1024 + c];
    hv[t] = f2bf(v);
  }
  *(uint4*)(dst + (size_t)c * 1024 + d0) = *(const uint4*)hv;
}

// ---------------------------------------------------------------------------
// QKV projection GEMM: C[4096x1024] = A(f32) * W^T(bf16), 128x128, BK=32.
// TRIPLE-buffered LDS (72 KB -> 2 blocks/CU). Per step: issue stage(t+2),
// compute buf[t%3], then s_waitcnt vmcnt(6) (waits stage(t+1) only; stage(t+2)
// stays in flight across the raw s_barrier). Protocol verified in round 12.
// Grid: 768 blocks 1-D, XCD-clustered (768 = 8 xcd x 4 m-panels x 24 y).
// ---------------------------------------------------------------------------
__global__ __launch_bounds__(256, 2)
void proj_gemm(const float* __restrict__ Qm, const float* __restrict__ Tm,
               const float* __restrict__ Vm, const unsigned short* __restrict__ Wt,
               const float* __restrict__ bq, const float* __restrict__ bk,
               const float* __restrict__ bv, unsigned short* __restrict__ qb,
               unsigned short* __restrict__ kb, unsigned short* __restrict__ vtb) {
  __shared__ float Af[3][128 * 32];           // 48 KB
  __shared__ unsigned short Bt[3][128 * 32];  // 24 KB  (72 KB total)

  const int tid = threadIdx.x;
  const int lane = tid & 63;
  const int w = tid >> 6;
  const int g = lane >> 4, c = lane & 15;
  const int wm = w >> 1, wn = w & 1;

  const int orig = blockIdx.x;
  const int xcd = orig & 7;
  const int l = orig >> 3;          // 0..95
  const int bx = xcd * 4 + l / 24;  // 0..31
  const int by = l % 24;            // 0..23

  const int m0 = bx * 128;
  const int proj = by >> 3;
  const int n0 = (by & 7) * 128;

  const float* Asrc = (proj == 0) ? Qm : (proj == 1) ? Tm : Vm;
  const unsigned short* W = Wt + (size_t)proj * (1024u * 1024u);

  f32x4 acc[4][4];
#pragma unroll
  for (int i = 0; i < 4; ++i)
#pragma unroll
    for (int j = 0; j < 4; ++j) acc[i][j] = fzero();

  const int arow = w * 8 + (lane >> 3);  // A staging row within 32-row quarter
  const int ach = lane & 7;              // A 16B chunk (4 f32)
  const int brow = w * 16 + (lane >> 2); // B staging row within 64-row half
  const int bch = lane & 3;              // B 16B chunk (8 bf16)

  // 6 gld_lds per thread per stage (4 A + 2 B) -> vmcnt unit = 6.
#define PSTAGE(KT, BUF)                                                        \
  do {                                                                         \
    _Pragma("unroll")                                                          \
    for (int u = 0; u < 4; ++u) {                                              \
      const int row = u * 32 + arow;                                           \
      const int ch = ach ^ (row & 7);                                          \
      gld_lds16(Asrc + (size_t)(m0 + row) * 1024 + (KT) * 32 + ch * 4,         \
                &Af[BUF][(u * 32 + w * 8) * 32]);                              \
    }                                                                          \
    _Pragma("unroll")                                                          \
    for (int u = 0; u < 2; ++u) {                                              \
      const int row = u * 64 + brow;                                           \
      const int ch = bch ^ ((row >> 1) & 3);                                   \
      gld_lds16(W + (size_t)(n0 + row) * 1024 + (KT) * 32 + ch * 8,            \
                &Bt[BUF][(u * 64 + w * 16) * 32]);                             \
    }                                                                          \
  } while (0)

#define PBODY(KT, CUR, STG)                                                    \
  do {                                                                         \
    if ((KT) + 2 < 32) PSTAGE((KT) + 2, STG);                                  \
    bf16x8 af[4], bfr[4];                                                      \
    _Pragma("unroll")                                                          \
    for (int mi = 0; mi < 4; ++mi) {                                           \
      const int row = wm * 64 + mi * 16 + c;                                   \
      const int swz = row & 7;                                                 \
      const float4 fa =                                                        \
          *(const float4*)&Af[CUR][row * 32 + ((2 * g) ^ swz) * 4];            \
      const float4 fb =                                                        \
          *(const float4*)&Af[CUR][row * 32 + ((2 * g + 1) ^ swz) * 4];        \
      U8 u8;                                                                   \
      asm("v_cvt_pk_bf16_f32 %0, %1, %2"                                       \
          : "=v"(u8.u[0]) : "v"(fa.x), "v"(fa.y));                             \
      asm("v_cvt_pk_bf16_f32 %0, %1, %2"                                       \
          : "=v"(u8.u[1]) : "v"(fa.z), "v"(fa.w));                             \
      asm("v_cvt_pk_bf16_f32 %0, %1, %2"                                       \
          : "=v"(u8.u[2]) : "v"(fb.x), "v"(fb.y));                             \
      asm("v_cvt_pk_bf16_f32 %0, %1, %2"                                       \
          : "=v"(u8.u[3]) : "v"(fb.z), "v"(fb.w));                             \
      af[mi] = u8.v;                                                           \
    }                                                                          \
    _Pragma("unroll")                                                          \
    for (int ni = 0; ni < 4; ++ni) {                                           \
      const int row = wn * 64 + ni * 16 + c;                                   \
      bfr[ni] = *(const bf16x8*)&Bt[CUR][row * 32 +                            \
                                        ((g ^ ((row >> 1) & 3))) * 8];         \
    }                                                                          \
    __builtin_amdgcn_s_setprio(1);                                             \
    _Pragma("unroll")                                                          \
    for (int mi = 0; mi < 4; ++mi)                                             \
      _Pragma("unroll")                                                        \
      for (int ni = 0; ni < 4; ++ni)                                           \
        acc[mi][ni] = __builtin_amdgcn_mfma_f32_16x16x32_bf16(                 \
            af[mi], bfr[ni], acc[mi][ni], 0, 0, 0);                            \
    __builtin_amdgcn_s_setprio(0);                                             \
    asm volatile("s_waitcnt vmcnt(6)" ::: "memory");                           \
    __builtin_amdgcn_s_barrier();                                              \
    asm volatile("" ::: "memory");                                             \
  } while (0)

  // prologue: stages 0,1 in flight; wait stage 0 (leave stage 1's 6 pending)
  PSTAGE(0, 0);
  PSTAGE(1, 1);
  asm volatile("s_waitcnt vmcnt(6)" ::: "memory");
  __builtin_amdgcn_s_barrier();
  asm volatile("" ::: "memory");

  for (int kb2 = 0; kb2 < 30; kb2 += 3) {
    PBODY(kb2 + 0, 0, 2);
    PBODY(kb2 + 1, 1, 0);
    PBODY(kb2 + 2, 2, 1);
  }
  PBODY(30, 0, 2);
  PBODY(31, 1, 0);
#undef PBODY
#undef PSTAGE

  const float* bias = (proj == 0) ? bq : (proj == 1) ? bk : bv;
  if (proj < 2) {
    unsigned short* dptr = (proj == 0) ? qb : kb;
#pragma unroll
    for (int ni = 0; ni < 4; ++ni) {
      const int colb = n0 + wn * 64 + ni * 16 + c;  // 0..1023 = h*64+e
      const float bc = bias[colb];
      const int hh = colb >> 6, e = colb & 63;
#pragma unroll
      for (int mi = 0; mi < 4; ++mi)
#pragma unroll
        for (int r = 0; r < 4; ++r) {
          const int row = m0 + wm * 64 + mi * 16 + g * 4 + r;  // b*S+s
          const int bb = row >> 11, s = row & 2047;
          dptr[(((size_t)(bb * H_ + hh)) * S_ + s) * 64 + e] = f2bf(acc[mi][ni][r] + bc);
        }
    }
  } else {  // v stored transposed per head [B,H,E,S]; 4 s-values pack to b64
#pragma unroll
    for (int ni = 0; ni < 4; ++ni) {
      const int colb = n0 + wn * 64 + ni * 16 + c;
      const float bc = bias[colb];
      const int hh = colb >> 6, e = colb & 63;
#pragma unroll
      for (int mi = 0; mi < 4; ++mi) {
        const int rowb = m0 + wm * 64 + mi * 16 + g * 4;  // 4-aligned, no b-cross
        const int bb = rowb >> 11, s0 = rowb & 2047;
        const float v0 = acc[mi][ni][0] + bc, v1 = acc[mi][ni][1] + bc;
        const float v2 = acc[mi][ni][2] + bc, v3 = acc[mi][ni][3] + bc;
        uint2 pk;
        asm("v_cvt_pk_bf16_f32 %0, %1, %2" : "=v"(pk.x) : "v"(v0), "v"(v1));
        asm("v_cvt_pk_bf16_f32 %0, %1, %2" : "=v"(pk.y) : "v"(v2), "v"(v3));
        *(uint2*)&vtb[(((size_t)(bb * H_ + hh)) * 64 + e) * S_ + s0] = pk;
      }
    }
  }
}

// ---------------------------------------------------------------------------
// Flash attention v9 (round-14 verified): KVBLK=128 per barrier. 512 blocks
// (XCD-swizzled), 4 waves x 32 q. K [128][64] dbuf, V^T [64][128] dbuf,
// Pt 16 KB (80 KB total, 2 blocks/CU). Two 64-kv sub-tiles per barrier.
// ---------------------------------------------------------------------------
__global__ __launch_bounds__(256, 2)
void attn_kernel(const unsigned short* __restrict__ qb,
                 const unsigned short* __restrict__ kb,
                 const unsigned short* __restrict__ vtb,
                 unsigned short* __restrict__ att) {
  __shared__ unsigned short Kt[2][128 * 64];  // 32 KB
  __shared__ unsigned short Vt[2][64 * 128];  // 32 KB
  __shared__ unsigned short Pt[4][32 * 64];   // 16 KB

  const int tid = threadIdx.x;
  const int lane = tid & 63;
  const int w = tid >> 6;
  const int g = lane >> 4, c = lane & 15;

  const int orig = blockIdx.x;                    // 0..511
  const int logical = ((orig & 7) << 6) | (orig >> 3);
  const int qblk = logical & 15;                  // 16 q-blocks of 128 rows
  const int bh = logical >> 4;                    // b*16+h, 0..31
  const int hh = bh & 15, bz = bh >> 4;

  const int q0w = qblk * 128 + w * 32;            // wave's 32 q rows
  const unsigned short* qh = qb + (size_t)bh * S_ * 64;
  const unsigned short* kh = kb + (size_t)bh * S_ * 64;
  const unsigned short* vh = vtb + (size_t)bh * 64 * S_;

  bf16x8 aq[2][2];
#pragma unroll
  for (int m = 0; m < 2; ++m)
#pragma unroll
    for (int t = 0; t < 2; ++t)
      aq[m][t] = *(const bf16x8*)&qh[(size_t)(q0w + m * 16 + c) * 64 + t * 32 + g * 8];

  bf16x8 onesB;
#pragma unroll
  for (int i = 0; i < 8; ++i) onesB[i] = (short)0x3F80;

  f32x4 O[2][4];
  f32x4 accL[2];
#pragma unroll
  for (int m = 0; m < 2; ++m) {
#pragma unroll
    for (int ne = 0; ne < 4; ++ne) O[m][ne] = fzero();
    accL[m] = fzero();
  }

  constexpr float L2E = 1.4426950408889634f;
  const float S2 = 0.125f * L2E;
  const float B2 = 0.125f * L2E;

  int kaOff[2][4];     // K read [ks][mi]; sub s adds s*8192 bytes
  int vOff[2][2][4];   // V read [sub][ks][ne]
  int paOff[2][2], pwOff[2][4];
#pragma unroll
  for (int ks = 0; ks < 2; ++ks) {
#pragma unroll
    for (int mi = 0; mi < 4; ++mi) {
      const int row = mi * 16 + c;
      kaOff[ks][mi] = 2 * (row * 64 + ((ks * 4 + g) ^ (row & 7)) * 8);
    }
#pragma unroll
    for (int m = 0; m < 2; ++m)
      paOff[m][ks] = 2 * ((m * 16 + c) * 64 + ((ks * 4 + g) ^ (c & 7)) * 8);
  }
#pragma unroll
  for (int s = 0; s < 2; ++s)
#pragma unroll
    for (int ks = 0; ks < 2; ++ks)
#pragma unroll
      for (int ne = 0; ne < 4; ++ne) {
        const int e = ne * 16 + c;  // e&15 == c
        vOff[s][ks][ne] = 2 * (e * 128 + ((s * 8 + ks * 4 + g) ^ c) * 8);
      }
#pragma unroll
  for (int m = 0; m < 2; ++m)
#pragma unroll
    for (int mi = 0; mi < 4; ++mi)
      pwOff[m][mi] =
          2 * ((m * 16 + c) * 64 + ((2 * mi + (g >> 1)) ^ (c & 7)) * 8 + (g & 1) * 4);

  const int srowK = w * 8 + (lane >> 3);
  const int schK = (lane & 7) ^ (srowK & 7);
  const unsigned short* kS = kh + (size_t)srowK * 64 + schK * 8;
  const int rowV = w * 4 + (lane >> 4);
  const int jV = (lane & 15) ^ rowV;
  const unsigned short* vS = vh + (size_t)rowV * S_ + jV * 8;

  {  // prologue: stage tile 0 (128 kv) into buffer 0
#pragma unroll
    for (int u = 0; u < 4; ++u) {
      gld_lds16(kS + u * 2048, &Kt[0][(u * 32 + w * 8) * 64]);
      gld_lds16(vS + (size_t)u * 32768, &Vt[0][(u * 16 + w * 4) * 128]);
    }
  }
  __syncthreads();

#define ATTN_SUB(J0S, SB, CUR)                                                 \
  do {                                                                         \
    const int j0 = (J0S);                                                      \
    f32x4 sa[2][4];                                                            \
    _Pragma("unroll")                                                          \
    for (int m = 0; m < 2; ++m)                                                \
      _Pragma("unroll")                                                        \
      for (int mi = 0; mi < 4; ++mi) sa[m][mi] = fzero();                      \
    __builtin_amdgcn_s_setprio(1);                                             \
    _Pragma("unroll")                                                          \
    for (int ks = 0; ks < 2; ++ks)                                             \
      _Pragma("unroll")                                                        \
      for (int mi = 0; mi < 4; ++mi) {                                         \
        const bf16x8 ka = *(const bf16x8*)((const char*)&Kt[CUR][0] +          \
                                           (SB) * 8192 + kaOff[ks][mi]);       \
        sa[0][mi] = __builtin_amdgcn_mfma_f32_16x16x32_bf16(ka, aq[0][ks],     \
                                                            sa[0][mi], 0, 0, 0);\
        sa[1][mi] = __builtin_amdgcn_mfma_f32_16x16x32_bf16(ka, aq[1][ks],     \
                                                            sa[1][mi], 0, 0, 0);\
      }                                                                        \
    __builtin_amdgcn_s_setprio(0);                                             \
    const bool allUp = (j0 >= q0w + 32);                                       \
    const bool noneUp = (j0 + 63 <= q0w);                                      \
    _Pragma("unroll")                                                          \
    for (int m = 0; m < 2; ++m) {                                              \
      const int iq = q0w + m * 16 + c;                                         \
      _Pragma("unroll")                                                        \
      for (int mi = 0; mi < 4; ++mi) {                                         \
        float pv[4];                                                           \
        if (allUp || noneUp) {                                                 \
          const float bb = allUp ? B2 : 0.f;                                   \
          _Pragma("unroll")                                                    \
          for (int r = 0; r < 4; ++r) {                                        \
            const float v = sa[m][mi][r];                                      \
            pv[r] = __builtin_amdgcn_exp2f(                                    \
                (v > 0.1f) ? __builtin_fmaf(v, S2, bb) : bb);                  \
          }                                                                    \
        } else {                                                               \
          _Pragma("unroll")                                                    \
          for (int r = 0; r < 4; ++r) {                                        \
            const float v = sa[m][mi][r];                                      \
            const float bb = (j0 + mi * 16 + g * 4 + r > iq) ? B2 : 0.f;       \
            pv[r] = __builtin_amdgcn_exp2f(                                    \
                (v > 0.1f) ? __builtin_fmaf(v, S2, bb) : bb);                  \
          }                                                                    \
        }                                                                      \
        uint2 d;                                                               \
        asm("v_cvt_pk_bf16_f32 %0, %1, %2"                                     \
            : "=v"(d.x) : "v"(pv[0]), "v"(pv[1]));                             \
        asm("v_cvt_pk_bf16_f32 %0, %1, %2"                                     \
            : "=v"(d.y) : "v"(pv[2]), "v"(pv[3]));                             \
        *(uint2*)((char*)&Pt[w][0] + pwOff[m][mi]) = d;                        \
      }                                                                        \
    }                                                                          \
    asm volatile("s_waitcnt lgkmcnt(0)" ::: "memory");                         \
    __builtin_amdgcn_sched_barrier(0);                                         \
    __builtin_amdgcn_s_setprio(1);                                             \
    _Pragma("unroll")                                                          \
    for (int ks = 0; ks < 2; ++ks) {                                           \
      const bf16x8 pa0 =                                                       \
          *(const bf16x8*)((const char*)&Pt[w][0] + paOff[0][ks]);             \
      const bf16x8 pa1 =                                                       \
          *(const bf16x8*)((const char*)&Pt[w][0] + paOff[1][ks]);             \
      accL[0] = __builtin_amdgcn_mfma_f32_16x16x32_bf16(pa0, onesB, accL[0],   \
                                                        0, 0, 0);              \
      accL[1] = __builtin_amdgcn_mfma_f32_16x16x32_bf16(pa1, onesB, accL[1],   \
                                                        0, 0, 0);              \
      _Pragma("unroll")                                                        \
      for (int ne = 0; ne < 4; ++ne) {                                         \
        const bf16x8 bv8 = *(const bf16x8*)((const char*)&Vt[CUR][0] +         \
                                            vOff[SB][ks][ne]);                 \
        O[0][ne] = __builtin_amdgcn_mfma_f32_16x16x32_bf16(pa0, bv8, O[0][ne], \
                                                           0, 0, 0);           \
        O[1][ne] = __builtin_amdgcn_mfma_f32_16x16x32_bf16(pa1, bv8, O[1][ne], \
                                                           0, 0, 0);           \
      }                                                                        \
    }                                                                          \
    __builtin_amdgcn_s_setprio(0);                                             \
  } while (0)

#define ATTN_TILE(T, CUR)                                                      \
  do {                                                                         \
    if ((T) < 15) {                                                            \
      _Pragma("unroll")                                                        \
      for (int u = 0; u < 4; ++u) {                                            \
        gld_lds16(kS + 8192 + u * 2048, &Kt[CUR ^ 1][(u * 32 + w * 8) * 64]);  \
        gld_lds16(vS + 128 + (size_t)u * 32768,                                \
                  &Vt[CUR ^ 1][(u * 16 + w * 4) * 128]);                       \
      }                                                                        \
      kS += 8192; vS += 128;                                                   \
    }                                                                          \
    ATTN_SUB((T) * 128, 0, CUR);                                               \
    ATTN_SUB((T) * 128 + 64, 1, CUR);                                          \
    __syncthreads();                                                           \
  } while (0)

  for (int T = 0; T < 16; T += 2) {
    ATTN_TILE(T, 0);
    ATTN_TILE(T + 1, 1);
  }
#undef ATTN_TILE
#undef ATTN_SUB

#pragma unroll
  for (int m = 0; m < 2; ++m)
#pragma unroll
    for (int r = 0; r < 4; ++r) {
      const float il = 1.f / accL[m][r];
      const int qg = q0w + m * 16 + g * 4 + r;
      const size_t ro = ((size_t)(bz * S_ + qg)) * 1024 + hh * 64;
#pragma unroll
      for (int ne = 0; ne < 4; ++ne)
        att[ro + ne * 16 + c] = f2bf(O[m][ne][r] * il);
    }
}

// ---------------------------------------------------------------------------
// Output projection: out[4096x1024] = att(bf16) @ Wo + bo, -> f32 d_out.
// Grid: 256 blocks 1-D, XCD-clustered (256 = 8 xcd x 4 x-local x 8 y).
// ---------------------------------------------------------------------------
__global__ __launch_bounds__(256, 3)
void out_gemm(const unsigned short* __restrict__ att,
              const unsigned short* __restrict__ WoT,
              const float* __restrict__ bo, float* __restrict__ outp) {
  __shared__ unsigned short At[2][128 * 32];
  __shared__ unsigned short Bt[2][128 * 32];

  const int tid = threadIdx.x;
  const int lane = tid & 63;
  const int w = tid >> 6;
  const int g = lane >> 4, c = lane & 15;
  const int wm = w >> 1, wn = w & 1;

  const int orig = blockIdx.x;
  const int xcd = orig & 7;
  const int l = orig >> 3;          // 0..31
  const int bx = xcd * 4 + l / 8;   // 0..31
  const int by = l % 8;             // 0..7
  const int m0 = bx * 128;
  const int n0 = by * 128;

  f32x4 acc[4][4];
#pragma unroll
  for (int i = 0; i < 4; ++i)
#pragma unroll
    for (int j = 0; j < 4; ++j) acc[i][j] = fzero();

  const int srow = lane >> 2;
  const int sch = lane & 3;

  auto stage = [&](int kt, int buf) {
#pragma unroll
    for (int u = 0; u < 2; ++u) {
      const int row = u * 64 + w * 16 + srow;
      const int ch = sch ^ ((row >> 1) & 3);
      gld_lds16(att + (size_t)(m0 + row) * 1024 + kt * 32 + ch * 8,
                &At[buf][(u * 64 + w * 16) * 32]);
      gld_lds16(WoT + (size_t)(n0 + row) * 1024 + kt * 32 + ch * 8,
                &Bt[buf][(u * 64 + w * 16) * 32]);
    }
  };

  stage(0, 0);
  __syncthreads();

  for (int kt = 0; kt < 32; ++kt) {
    const int buf = kt & 1;
    if (kt < 31) stage(kt + 1, buf ^ 1);

    bf16x8 af[4], bfr[4];
#pragma unroll
    for (int mi = 0; mi < 4; ++mi) {
      const int row = wm * 64 + mi * 16 + c;
      af[mi] = *(const bf16x8*)&At[buf][row * 32 + ((g ^ ((row >> 1) & 3))) * 8];
    }
#pragma unroll
    for (int ni = 0; ni < 4; ++ni) {
      const int row = wn * 64 + ni * 16 + c;
      bfr[ni] = *(const bf16x8*)&Bt[buf][row * 32 + ((g ^ ((row >> 1) & 3))) * 8];
    }
#pragma unroll
    for (int mi = 0; mi < 4; ++mi)
#pragma unroll
      for (int ni = 0; ni < 4; ++ni)
        acc[mi][ni] = __builtin_amdgcn_mfma_f32_16x16x32_bf16(af[mi], bfr[ni],
                                                              acc[mi][ni], 0, 0, 0);
    __syncthreads();
  }

#pragma unroll
  for (int ni = 0; ni < 4; ++ni) {
    const int colb = n0 + wn * 64 + ni * 16 + c;
    const float bc = bo[colb];
#pragma unroll
    for (int mi = 0; mi < 4; ++mi)
#pragma unroll
      for (int r = 0; r < 4; ++r) {
        const int row = m0 + wm * 64 + mi * 16 + g * 4 + r;
        outp[(size_t)row * 1024 + colb] = acc[mi][ni][r] + bc;
      }
  }
}

// ---------------------------------------------------------------------------
extern "C" void kernel_launch(void* const* d_in, const int* in_sizes, int n_in,
                              void* d_out, int out_size, void* d_ws, size_t ws_size,
                              hipStream_t stream) {
  const float* Q  = (const float*)d_in[0];
  const float* T  = (const float*)d_in[1];
  const float* V  = (const float*)d_in[2];
  const float* Wq = (const float*)d_in[3];
  const float* bq = (const float*)d_in[4];
  const float* Wk = (const float*)d_in[5];
  const float* bk = (const float*)d_in[6];
  const float* Wv = (const float*)d_in[7];
  const float* bv = (const float*)d_in[8];
  const float* Wo = (const float*)d_in[9];
  const float* bo = (const float*)d_in[10];

  const size_t MB = 1024ull * 1024ull;
  if (ws_size < 40 * MB) return;  // need 40 MB scratch; clean fail otherwise

  uint8_t* ws = (uint8_t*)d_ws;
  unsigned short* Wt  = (unsigned short*)(ws);            // 8MB: WqT,WkT,WvT,WoT
  unsigned short* qb  = (unsigned short*)(ws + 8 * MB);   // 8MB  [B,H,S,E]
  unsigned short* kb  = (unsigned short*)(ws + 16 * MB);  // 8MB  [B,H,S,E]
  unsigned short* vtb = (unsigned short*)(ws + 24 * MB);  // 8MB  [B,H,E,S]
  unsigned short* attb = (unsigned short*)(ws + 32 * MB); // 8MB  [B,S,H*E]

  prep_weights<<<dim3(512, 1, 4), 256, 0, stream>>>(Wq, Wk, Wv, Wo, Wt);
  proj_gemm<<<dim3(768), 256, 0, stream>>>(Q, T, V, Wt, bq, bk, bv,
                                           qb, kb, vtb);
  attn_kernel<<<dim3(512), 256, 0, stream>>>(qb, kb, vtb, attb);
  out_gemm<<<dim3(256), 256, 0, stream>>>(attb, Wt + 3ull * 1024ull * 1024ull,
                                          bo, (float*)d_out);
}

// Round 17
// 138.297 us; speedup vs baseline: 1.0330x; 1.0330x over previous
//
#include <hip/hip_runtime.h>
#include <stdint.h>

// MultiHeadAttentionLayer: bf16-MFMA pipeline, f32 output.
// r14-best config + XCD-ALIGNED bf16 A pre-pass: convert_a writes panel p from
// the same XCD that proj's T1 decode assigns panel p to, so proj's A staging
// hits that XCD's L2 (3MB/XCD < 4MB) instead of HBM (~900cy -> ~200cy).
//   prep_weights: Wq/Wk/Wv -> W^T bf16; Wo -> Wo^T bf16
//   convert_a:    Q/T/V f32 -> bf16, XCD-clustered panel mapping
//   proj_gemm:    r6-verified all-bf16 gld_lds dbuf 128x128 (32KB LDS); T1 grid
//   attn_kernel:  r14-verified KVBLK=128 dbuf
//   out_gemm:     r14-verified dbuf + T1 grid -> d_out (f32)
// Aliasing (r6-verified): aQ,aT live in d_out (dead until out_gemm); aV in attb
// (dead until attn writes it, after proj consumed it).

typedef __attribute__((ext_vector_type(8))) short bf16x8;
typedef __attribute__((ext_vector_type(4))) float f32x4;

#define DEVFN static __device__ __forceinline__

static constexpr int S_ = 2048;
static constexpr int H_ = 16;

DEVFN unsigned short f2bf(float x) {
  union { float f; uint32_t u; } v; v.f = x;
  const uint32_t r = v.u + 0x7fffu + ((v.u >> 16) & 1u);  // RNE
  return (unsigned short)(r >> 16);
}

DEVFN f32x4 fzero() { f32x4 v = {0.f, 0.f, 0.f, 0.f}; return v; }

// global -> LDS direct copy, 16B per lane; LDS dest must be wave-uniform base.
DEVFN void gld_lds16(const void* g, void* lds) {
  __builtin_amdgcn_global_load_lds(
      (const __attribute__((address_space(1))) void*)g,
      (__attribute__((address_space(3))) void*)lds, 16, 0, 0);
}

// ---------------------------------------------------------------------------
// Weight prep: dst[c][d] = W[h=c>>6][d][e=c&63] (z<3) or Wo[d][c] (z==3), bf16
// ---------------------------------------------------------------------------
__global__ void prep_weights(const float* __restrict__ Wq, const float* __restrict__ Wk,
                             const float* __restrict__ Wv, const float* __restrict__ Wo,
                             unsigned short* __restrict__ dstBase) {
  const int z = blockIdx.z;
  const float* src = (z == 0) ? Wq : (z == 1) ? Wk : (z == 2) ? Wv : Wo;
  unsigned short* dst = dstBase + (size_t)z * (1024u * 1024u);
  const int idx = blockIdx.x * 256 + threadIdx.x;  // 131072 threads
  const int c = idx & 1023;
  const int d0 = (idx >> 10) << 3;
  unsigned short hv[8];
#pragma unroll
  for (int t = 0; t < 8; ++t) {
    const int d = d0 + t;
    const float v = (z < 3) ? src[(size_t)((c >> 6) * 1024 + d) * 64 + (c & 63)]
                            : src[(size_t)d * 1024 + c];
    hv[t] = f2bf(v);
  }
  *(uint4*)(dst + (size_t)c * 1024 + d0) = *(const uint4*)hv;
}

// ---------------------------------------------------------------------------
// A convert, XCD-aligned: panel p (128 rows) is written by blocks whose
// hardware XCD (orig&7, round-robin heuristic) == p>>2 — matching proj's T1
// decode (bx = xcd*4 + l/24). Bijective: orig in [0,2048) -> (p in [0,32),
// inner in [0,64)); each block converts 2048 f32 -> bf16.
// ---------------------------------------------------------------------------
__global__ void convert_a(const float* __restrict__ Qm, const float* __restrict__ Tm,
                          const float* __restrict__ Vm, unsigned short* __restrict__ aq,
                          unsigned short* __restrict__ at2, unsigned short* __restrict__ av) {
  const int z = blockIdx.z;
  const float* s = (z == 0) ? Qm : (z == 1) ? Tm : Vm;
  unsigned short* d = (z == 0) ? aq : (z == 1) ? at2 : av;
  const int orig = blockIdx.x;            // 0..2047
  const int xcd = orig & 7;
  const int j = orig >> 3;                // 0..255
  const int p = xcd * 4 + (j >> 6);       // panel 0..31, on xcd = p>>2
  const int inner = j & 63;               // 64 blocks per panel
  const size_t i = (size_t)p * 131072 + (size_t)inner * 2048 +
                   (size_t)threadIdx.x * 8;
  const float4 f0 = *(const float4*)(s + i);
  const float4 f1 = *(const float4*)(s + i + 4);
  uint32_t d0, d1, d2, d3;
  asm("v_cvt_pk_bf16_f32 %0, %1, %2" : "=v"(d0) : "v"(f0.x), "v"(f0.y));
  asm("v_cvt_pk_bf16_f32 %0, %1, %2" : "=v"(d1) : "v"(f0.z), "v"(f0.w));
  asm("v_cvt_pk_bf16_f32 %0, %1, %2" : "=v"(d2) : "v"(f1.x), "v"(f1.y));
  asm("v_cvt_pk_bf16_f32 %0, %1, %2" : "=v"(d3) : "v"(f1.z), "v"(f1.w));
  uint4 o; o.x = d0; o.y = d1; o.z = d2; o.w = d3;
  *(uint4*)(d + i) = o;
}

// ---------------------------------------------------------------------------
// QKV projection GEMM: C[4096x1024] = A(bf16) * W^T(bf16), 128x128, BK=32.
// r6-verified structure: BOTH operands via global_load_lds (pre-swizzled
// source), 2-phase double buffer, 32KB LDS. Grid: 768 1-D, T1 XCD-clustered
// (768 = 8 xcd x 4 m-panels x 24 y) -> A panels read from the local L2.
// ---------------------------------------------------------------------------
__global__ __launch_bounds__(256, 4)
void proj_gemm(const unsigned short* __restrict__ Aq,
               const unsigned short* __restrict__ At2,
               const unsigned short* __restrict__ Av,
               const unsigned short* __restrict__ Wt,
               const float* __restrict__ bq, const float* __restrict__ bk,
               const float* __restrict__ bv, unsigned short* __restrict__ qb,
               unsigned short* __restrict__ kb, unsigned short* __restrict__ vtb) {
  __shared__ unsigned short At[2][128 * 32];
  __shared__ unsigned short Bt[2][128 * 32];

  const int tid = threadIdx.x;
  const int lane = tid & 63;
  const int w = tid >> 6;
  const int g = lane >> 4, c = lane & 15;
  const int wm = w >> 1, wn = w & 1;

  const int orig = blockIdx.x;
  const int xcd = orig & 7;
  const int l = orig >> 3;          // 0..95
  const int bx = xcd * 4 + l / 24;  // 0..31  (panel bx on xcd = bx>>2)
  const int by = l % 24;            // 0..23

  const int m0 = bx * 128;
  const int proj = by >> 3;
  const int n0 = (by & 7) * 128;

  const unsigned short* Abf = (proj == 0) ? Aq : (proj == 1) ? At2 : Av;
  const unsigned short* W = Wt + (size_t)proj * (1024u * 1024u);

  f32x4 acc[4][4];
#pragma unroll
  for (int i = 0; i < 4; ++i)
#pragma unroll
    for (int j = 0; j < 4; ++j) acc[i][j] = fzero();

  const int srow = lane >> 2;   // 0..15 row within 16-row wave slice
  const int sch = lane & 3;     // 16B chunk 0..3

  auto stage = [&](int kt, int buf) {
#pragma unroll
    for (int u = 0; u < 2; ++u) {
      const int row = u * 64 + w * 16 + srow;
      const int ch = sch ^ ((row >> 1) & 3);
      gld_lds16(Abf + (size_t)(m0 + row) * 1024 + kt * 32 + ch * 8,
                &At[buf][(u * 64 + w * 16) * 32]);
      gld_lds16(W + (size_t)(n0 + row) * 1024 + kt * 32 + ch * 8,
                &Bt[buf][(u * 64 + w * 16) * 32]);
    }
  };

  stage(0, 0);
  __syncthreads();

  for (int kt = 0; kt < 32; ++kt) {
    const int buf = kt & 1;
    if (kt < 31) stage(kt + 1, buf ^ 1);

    bf16x8 af[4], bfr[4];
#pragma unroll
    for (int mi = 0; mi < 4; ++mi) {
      const int row = wm * 64 + mi * 16 + c;
      af[mi] = *(const bf16x8*)&At[buf][row * 32 + ((g ^ ((row >> 1) & 3))) * 8];
    }
#pragma unroll
    for (int ni = 0; ni < 4; ++ni) {
      const int row = wn * 64 + ni * 16 + c;
      bfr[ni] = *(const bf16x8*)&Bt[buf][row * 32 + ((g ^ ((row >> 1) & 3))) * 8];
    }
    __builtin_amdgcn_s_setprio(1);
#pragma unroll
    for (int mi = 0; mi < 4; ++mi)
#pragma unroll
      for (int ni = 0; ni < 4; ++ni)
        acc[mi][ni] = __builtin_amdgcn_mfma_f32_16x16x32_bf16(af[mi], bfr[ni],
                                                              acc[mi][ni], 0, 0, 0);
    __builtin_amdgcn_s_setprio(0);
    __syncthreads();  // drains vmcnt: prefetched tile complete, cur tile free
  }

  const float* bias = (proj == 0) ? bq : (proj == 1) ? bk : bv;
  if (proj < 2) {
    unsigned short* dptr = (proj == 0) ? qb : kb;
#pragma unroll
    for (int ni = 0; ni < 4; ++ni) {
      const int colb = n0 + wn * 64 + ni * 16 + c;  // 0..1023 = h*64+e
      const float bc = bias[colb];
      const int hh = colb >> 6, e = colb & 63;
#pragma unroll
      for (int mi = 0; mi < 4; ++mi)
#pragma unroll
        for (int r = 0; r < 4; ++r) {
          const int row = m0 + wm * 64 + mi * 16 + g * 4 + r;  // b*S+s
          const int bb = row >> 11, s = row & 2047;
          dptr[(((size_t)(bb * H_ + hh)) * S_ + s) * 64 + e] = f2bf(acc[mi][ni][r] + bc);
        }
    }
  } else {  // v stored transposed per head [B,H,E,S]; 4 s-values pack to b64
#pragma unroll
    for (int ni = 0; ni < 4; ++ni) {
      const int colb = n0 + wn * 64 + ni * 16 + c;
      const float bc = bias[colb];
      const int hh = colb >> 6, e = colb & 63;
#pragma unroll
      for (int mi = 0; mi < 4; ++mi) {
        const int rowb = m0 + wm * 64 + mi * 16 + g * 4;  // 4-aligned, no b-cross
        const int bb = rowb >> 11, s0 = rowb & 2047;
        const float v0 = acc[mi][ni][0] + bc, v1 = acc[mi][ni][1] + bc;
        const float v2 = acc[mi][ni][2] + bc, v3 = acc[mi][ni][3] + bc;
        uint2 pk;
        asm("v_cvt_pk_bf16_f32 %0, %1, %2" : "=v"(pk.x) : "v"(v0), "v"(v1));
        asm("v_cvt_pk_bf16_f32 %0, %1, %2" : "=v"(pk.y) : "v"(v2), "v"(v3));
        *(uint2*)&vtb[(((size_t)(bb * H_ + hh)) * 64 + e) * S_ + s0] = pk;
      }
    }
  }
}

// ---------------------------------------------------------------------------
// Flash attention v9 (round-14 verified): KVBLK=128 per barrier. 512 blocks
// (XCD-swizzled), 4 waves x 32 q. K [128][64] dbuf, V^T [64][128] dbuf,
// Pt 16 KB (80 KB total, 2 blocks/CU). Two 64-kv sub-tiles per barrier.
// ---------------------------------------------------------------------------
__global__ __launch_bounds__(256, 2)
void attn_kernel(const unsigned short* __restrict__ qb,
                 const unsigned short* __restrict__ kb,
                 const unsigned short* __restrict__ vtb,
                 unsigned short* __restrict__ att) {
  __shared__ unsigned short Kt[2][128 * 64];  // 32 KB
  __shared__ unsigned short Vt[2][64 * 128];  // 32 KB
  __shared__ unsigned short Pt[4][32 * 64];   // 16 KB

  const int tid = threadIdx.x;
  const int lane = tid & 63;
  const int w = tid >> 6;
  const int g = lane >> 4, c = lane & 15;

  const int orig = blockIdx.x;                    // 0..511
  const int logical = ((orig & 7) << 6) | (orig >> 3);
  const int qblk = logical & 15;                  // 16 q-blocks of 128 rows
  const int bh = logical >> 4;                    // b*16+h, 0..31
  const int hh = bh & 15, bz = bh >> 4;

  const int q0w = qblk * 128 + w * 32;            // wave's 32 q rows
  const unsigned short* qh = qb + (size_t)bh * S_ * 64;
  const unsigned short* kh = kb + (size_t)bh * S_ * 64;
  const unsigned short* vh = vtb + (size_t)bh * 64 * S_;

  bf16x8 aq[2][2];
#pragma unroll
  for (int m = 0; m < 2; ++m)
#pragma unroll
    for (int t = 0; t < 2; ++t)
      aq[m][t] = *(const bf16x8*)&qh[(size_t)(q0w + m * 16 + c) * 64 + t * 32 + g * 8];

  bf16x8 onesB;
#pragma unroll
  for (int i = 0; i < 8; ++i) onesB[i] = (short)0x3F80;

  f32x4 O[2][4];
  f32x4 accL[2];
#pragma unroll
  for (int m = 0; m < 2; ++m) {
#pragma unroll
    for (int ne = 0; ne < 4; ++ne) O[m][ne] = fzero();
    accL[m] = fzero();
  }

  constexpr float L2E = 1.4426950408889634f;
  const float S2 = 0.125f * L2E;
  const float B2 = 0.125f * L2E;

  int kaOff[2][4];     // K read [ks][mi]; sub s adds s*8192 bytes
  int vOff[2][2][4];   // V read [sub][ks][ne]
  int paOff[2][2], pwOff[2][4];
#pragma unroll
  for (int ks = 0; ks < 2; ++ks) {
#pragma unroll
    for (int mi = 0; mi < 4; ++mi) {
      const int row = mi * 16 + c;
      kaOff[ks][mi] = 2 * (row * 64 + ((ks * 4 + g) ^ (row & 7)) * 8);
    }
#pragma unroll
    for (int m = 0; m < 2; ++m)
      paOff[m][ks] = 2 * ((m * 16 + c) * 64 + ((ks * 4 + g) ^ (c & 7)) * 8);
  }
#pragma unroll
  for (int s = 0; s < 2; ++s)
#pragma unroll
    for (int ks = 0; ks < 2; ++ks)
#pragma unroll
      for (int ne = 0; ne < 4; ++ne) {
        const int e = ne * 16 + c;  // e&15 == c
        vOff[s][ks][ne] = 2 * (e * 128 + ((s * 8 + ks * 4 + g) ^ c) * 8);
      }
#pragma unroll
  for (int m = 0; m < 2; ++m)
#pragma unroll
    for (int mi = 0; mi < 4; ++mi)
      pwOff[m][mi] =
          2 * ((m * 16 + c) * 64 + ((2 * mi + (g >> 1)) ^ (c & 7)) * 8 + (g & 1) * 4);

  const int srowK = w * 8 + (lane >> 3);
  const int schK = (lane & 7) ^ (srowK & 7);
  const unsigned short* kS = kh + (size_t)srowK * 64 + schK * 8;
  const int rowV = w * 4 + (lane >> 4);
  const int jV = (lane & 15) ^ rowV;
  const unsigned short* vS = vh + (size_t)rowV * S_ + jV * 8;

  {  // prologue: stage tile 0 (128 kv) into buffer 0
#pragma unroll
    for (int u = 0; u < 4; ++u) {
      gld_lds16(kS + u * 2048, &Kt[0][(u * 32 + w * 8) * 64]);
      gld_lds16(vS + (size_t)u * 32768, &Vt[0][(u * 16 + w * 4) * 128]);
    }
  }
  __syncthreads();

#define ATTN_SUB(J0S, SB, CUR)                                                 \
  do {                                                                         \
    const int j0 = (J0S);                                                      \
    f32x4 sa[2][4];                                                            \
    _Pragma("unroll")                                                          \
    for (int m = 0; m < 2; ++m)                                                \
      _Pragma("unroll")                                                        \
      for (int mi = 0; mi < 4; ++mi) sa[m][mi] = fzero();                      \
    __builtin_amdgcn_s_setprio(1);                                             \
    _Pragma("unroll")                                                          \
    for (int ks = 0; ks < 2; ++ks)                                             \
      _Pragma("unroll")                                                        \
      for (int mi = 0; mi < 4; ++mi) {                                         \
        const bf16x8 ka = *(const bf16x8*)((const char*)&Kt[CUR][0] +          \
                                           (SB) * 8192 + kaOff[ks][mi]);       \
        sa[0][mi] = __builtin_amdgcn_mfma_f32_16x16x32_bf16(ka, aq[0][ks],     \
                                                            sa[0][mi], 0, 0, 0);\
        sa[1][mi] = __builtin_amdgcn_mfma_f32_16x16x32_bf16(ka, aq[1][ks],     \
                                                            sa[1][mi], 0, 0, 0);\
      }                                                                        \
    __builtin_amdgcn_s_setprio(0);                                             \
    const bool allUp = (j0 >= q0w + 32);                                       \
    const bool noneUp = (j0 + 63 <= q0w);                                      \
    _Pragma("unroll")                                                          \
    for (int m = 0; m < 2; ++m) {                                              \
      const int iq = q0w + m * 16 + c;                                         \
      _Pragma("unroll")                                                        \
      for (int mi = 0; mi < 4; ++mi) {                                         \
        float pv[4];                                                           \
        if (allUp || noneUp) {                                                 \
          const float bb = allUp ? B2 : 0.f;                                   \
          _Pragma("unroll")                                                    \
          for (int r = 0; r < 4; ++r) {                                        \
            const float v = sa[m][mi][r];                                      \
            pv[r] = __builtin_amdgcn_exp2f(                                    \
                (v > 0.1f) ? __builtin_fmaf(v, S2, bb) : bb);                  \
          }                                                                    \
        } else {                                                               \
          _Pragma("unroll")                                                    \
          for (int r = 0; r < 4; ++r) {                                        \
            const float v = sa[m][mi][r];                                      \
            const float bb = (j0 + mi * 16 + g * 4 + r > iq) ? B2 : 0.f;       \
            pv[r] = __builtin_amdgcn_exp2f(                                    \
                (v > 0.1f) ? __builtin_fmaf(v, S2, bb) : bb);                  \
          }                                                                    \
        }                                                                      \
        uint2 d;                                                               \
        asm("v_cvt_pk_bf16_f32 %0, %1, %2"                                     \
            : "=v"(d.x) : "v"(pv[0]), "v"(pv[1]));                             \
        asm("v_cvt_pk_bf16_f32 %0, %1, %2"                                     \
            : "=v"(d.y) : "v"(pv[2]), "v"(pv[3]));                             \
        *(uint2*)((char*)&Pt[w][0] + pwOff[m][mi]) = d;                        \
      }                                                                        \
    }                                                                          \
    asm volatile("s_waitcnt lgkmcnt(0)" ::: "memory");                         \
    __builtin_amdgcn_sched_barrier(0);                                         \
    __builtin_amdgcn_s_setprio(1);                                             \
    _Pragma("unroll")                                                          \
    for (int ks = 0; ks < 2; ++ks) {                                           \
      const bf16x8 pa0 =                                                       \
          *(const bf16x8*)((const char*)&Pt[w][0] + paOff[0][ks]);             \
      const bf16x8 pa1 =                                                       \
          *(const bf16x8*)((const char*)&Pt[w][0] + paOff[1][ks]);             \
      accL[0] = __builtin_amdgcn_mfma_f32_16x16x32_bf16(pa0, onesB, accL[0],   \
                                                        0, 0, 0);              \
      accL[1] = __builtin_amdgcn_mfma_f32_16x16x32_bf16(pa1, onesB, accL[1],   \
                                                        0, 0, 0);              \
      _Pragma("unroll")                                                        \
      for (int ne = 0; ne < 4; ++ne) {                                         \
        const bf16x8 bv8 = *(const bf16x8*)((const char*)&Vt[CUR][0] +         \
                                            vOff[SB][ks][ne]);                 \
        O[0][ne] = __builtin_amdgcn_mfma_f32_16x16x32_bf16(pa0, bv8, O[0][ne], \
                                                           0, 0, 0);           \
        O[1][ne] = __builtin_amdgcn_mfma_f32_16x16x32_bf16(pa1, bv8, O[1][ne], \
                                                           0, 0, 0);           \
      }                                                                        \
    }                                                                          \
    __builtin_amdgcn_s_setprio(0);                                             \
  } while (0)

#define ATTN_TILE(T, CUR)                                                      \
  do {                                                                         \
    if ((T) < 15) {                                                            \
      _Pragma("unroll")                                                        \
      for (int u = 0; u < 4; ++u) {                                            \
        gld_lds16(kS + 8192 + u * 2048, &Kt[CUR ^ 1][(u * 32 + w * 8) * 64]);  \
        gld_lds16(vS + 128 + (size_t)u * 32768,                                \
                  &Vt[CUR ^ 1][(u * 16 + w * 4) * 128]);                       \
      }                                                                        \
      kS += 8192; vS += 128;                                                   \
    }                                                                          \
    ATTN_SUB((T) * 128, 0, CUR);                                               \
    ATTN_SUB((T) * 128 + 64, 1, CUR);                                          \
    __syncthreads();                                                           \
  } while (0)

  for (int T = 0; T < 16; T += 2) {
    ATTN_TILE(T, 0);
    ATTN_TILE(T + 1, 1);
  }
#undef ATTN_TILE
#undef ATTN_SUB

#pragma unroll
  for (int m = 0; m < 2; ++m)
#pragma unroll
    for (int r = 0; r < 4; ++r) {
      const float il = 1.f / accL[m][r];
      const int qg = q0w + m * 16 + g * 4 + r;
      const size_t ro = ((size_t)(bz * S_ + qg)) * 1024 + hh * 64;
#pragma unroll
      for (int ne = 0; ne < 4; ++ne)
        att[ro + ne * 16 + c] = f2bf(O[m][ne][r] * il);
    }
}

// ---------------------------------------------------------------------------
// Output projection: out[4096x1024] = att(bf16) @ Wo + bo, -> f32 d_out.
// Grid: 256 blocks 1-D, XCD-clustered (256 = 8 xcd x 4 x-local x 8 y).
// ---------------------------------------------------------------------------
__global__ __launch_bounds__(256, 3)
void out_gemm(const unsigned short* __restrict__ att,
              const unsigned short* __restrict__ WoT,
              const float* __restrict__ bo, float* __restrict__ outp) {
  __shared__ unsigned short At[2][128 * 32];
  __shared__ unsigned short Bt[2][128 * 32];

  const int tid = threadIdx.x;
  const int lane = tid & 63;
  const int w = tid >> 6;
  const int g = lane >> 4, c = lane & 15;
  const int wm = w >> 1, wn = w & 1;

  const int orig = blockIdx.x;
  const int xcd = orig & 7;
  const int l = orig >> 3;          // 0..31
  const int bx = xcd * 4 + l / 8;   // 0..31
  const int by = l % 8;             // 0..7
  const int m0 = bx * 128;
  const int n0 = by * 128;

  f32x4 acc[4][4];
#pragma unroll
  for (int i = 0; i < 4; ++i)
#pragma unroll
    for (int j = 0; j < 4; ++j) acc[i][j] = fzero();

  const int srow = lane >> 2;
  const int sch = lane & 3;

  auto stage = [&](int kt, int buf) {
#pragma unroll
    for (int u = 0; u < 2; ++u) {
      const int row = u * 64 + w * 16 + srow;
      const int ch = sch ^ ((row >> 1) & 3);
      gld_lds16(att + (size_t)(m0 + row) * 1024 + kt * 32 + ch * 8,
                &At[buf][(u * 64 + w * 16) * 32]);
      gld_lds16(WoT + (size_t)(n0 + row) * 1024 + kt * 32 + ch * 8,
                &Bt[buf][(u * 64 + w * 16) * 32]);
    }
  };

  stage(0, 0);
  __syncthreads();

  for (int kt = 0; kt < 32; ++kt) {
    const int buf = kt & 1;
    if (kt < 31) stage(kt + 1, buf ^ 1);

    bf16x8 af[4], bfr[4];
#pragma unroll
    for (int mi = 0; mi < 4; ++mi) {
      const int row = wm * 64 + mi * 16 + c;
      af[mi] = *(const bf16x8*)&At[buf][row * 32 + ((g ^ ((row >> 1) & 3))) * 8];
    }
#pragma unroll
    for (int ni = 0; ni < 4; ++ni) {
      const int row = wn * 64 + ni * 16 + c;
      bfr[ni] = *(const bf16x8*)&Bt[buf][row * 32 + ((g ^ ((row >> 1) & 3))) * 8];
    }
#pragma unroll
    for (int mi = 0; mi < 4; ++mi)
#pragma unroll
      for (int ni = 0; ni < 4; ++ni)
        acc[mi][ni] = __builtin_amdgcn_mfma_f32_16x16x32_bf16(af[mi], bfr[ni],
                                                              acc[mi][ni], 0, 0, 0);
    __syncthreads();
  }

#pragma unroll
  for (int ni = 0; ni < 4; ++ni) {
    const int colb = n0 + wn * 64 + ni * 16 + c;
    const float bc = bo[colb];
#pragma unroll
    for (int mi = 0; mi < 4; ++mi)
#pragma unroll
      for (int r = 0; r < 4; ++r) {
        const int row = m0 + wm * 64 + mi * 16 + g * 4 + r;
        outp[(size_t)row * 1024 + colb] = acc[mi][ni][r] + bc;
      }
  }
}

// ---------------------------------------------------------------------------
extern "C" void kernel_launch(void* const* d_in, const int* in_sizes, int n_in,
                              void* d_out, int out_size, void* d_ws, size_t ws_size,
                              hipStream_t stream) {
  const float* Q  = (const float*)d_in[0];
  const float* T  = (const float*)d_in[1];
  const float* V  = (const float*)d_in[2];
  const float* Wq = (const float*)d_in[3];
  const float* bq = (const float*)d_in[4];
  const float* Wk = (const float*)d_in[5];
  const float* bk = (const float*)d_in[6];
  const float* Wv = (const float*)d_in[7];
  const float* bv = (const float*)d_in[8];
  const float* Wo = (const float*)d_in[9];
  const float* bo = (const float*)d_in[10];

  const size_t MB = 1024ull * 1024ull;
  if (ws_size < 40 * MB) return;  // need 40 MB scratch; clean fail otherwise

  uint8_t* ws = (uint8_t*)d_ws;
  unsigned short* Wt  = (unsigned short*)(ws);            // 8MB: WqT,WkT,WvT,WoT
  unsigned short* qb  = (unsigned short*)(ws + 8 * MB);   // 8MB  [B,H,S,E]
  unsigned short* kb  = (unsigned short*)(ws + 16 * MB);  // 8MB  [B,H,S,E]
  unsigned short* vtb = (unsigned short*)(ws + 24 * MB);  // 8MB  [B,H,E,S]
  unsigned short* attb = (unsigned short*)(ws + 32 * MB); // 8MB  [B,S,H*E]

  // bf16 A-matrices: Q,T share d_out (16MB, dead until out_gemm); V uses the
  // attb slot (free until attn runs — proj consumes aV before attn writes it).
  unsigned short* aQ = (unsigned short*)d_out;            // 8MB
  unsigned short* aT = aQ + 4ull * 1024ull * 1024ull;     // 8MB
  unsigned short* aV = attb;                              // 8MB (time-shared)

  prep_weights<<<dim3(512, 1, 4), 256, 0, stream>>>(Wq, Wk, Wv, Wo, Wt);
  convert_a<<<dim3(2048, 1, 3), 256, 0, stream>>>(Q, T, V, aQ, aT, aV);
  proj_gemm<<<dim3(768), 256, 0, stream>>>(aQ, aT, aV, Wt, bq, bk, bv,
                                           qb, kb, vtb);
  attn_kernel<<<dim3(512), 256, 0, stream>>>(qb, kb, vtb, attb);
  out_gemm<<<dim3(256), 256, 0, stream>>>(attb, Wt + 3ull * 1024ull * 1024ull,
                                          bo, (float*)d_out);
}

// Round 18
// 131.428 us; speedup vs baseline: 1.0870x; 1.0523x over previous
//
#include <hip/hip_runtime.h>
#include <stdint.h>

// MultiHeadAttentionLayer: bf16-MFMA pipeline, f32 output.
// ROUND-14 VERIFIED BEST (131.57 us), restored byte-for-byte.
//   prep_weights: Wq/Wk/Wv ([H,D,E] f32) -> W^T bf16 [H*E][D]; Wo -> Wo^T bf16
//   proj_gemm:    A staged as f32 via global_load_lds; f32->bf16 fused into the
//                 LDS fragment read (cvt_pk). B bf16 via global_load_lds. T1 grid.
//   attn_kernel:  swapped QK^T, static-max, 32 q/wave, dbuf 128-kv tiles.
//   out_gemm:     double-buffered; att[4096x1024] @ Wo^T + bo -> d_out (f32). T1.

typedef __attribute__((ext_vector_type(8))) short bf16x8;
typedef __attribute__((ext_vector_type(4))) float f32x4;

#define DEVFN static __device__ __forceinline__

static constexpr int S_ = 2048;
static constexpr int H_ = 16;

DEVFN unsigned short f2bf(float x) {
  union { float f; uint32_t u; } v; v.f = x;
  const uint32_t r = v.u + 0x7fffu + ((v.u >> 16) & 1u);  // RNE
  return (unsigned short)(r >> 16);
}

DEVFN f32x4 fzero() { f32x4 v = {0.f, 0.f, 0.f, 0.f}; return v; }

union U8 { uint32_t u[4]; bf16x8 v; };

// global -> LDS direct copy, 16B per lane; LDS dest must be wave-uniform base.
DEVFN void gld_lds16(const void* g, void* lds) {
  __builtin_amdgcn_global_load_lds(
      (const __attribute__((address_space(1))) void*)g,
      (__attribute__((address_space(3))) void*)lds, 16, 0, 0);
}

// ---------------------------------------------------------------------------
// Weight prep: dst[c][d] = W[h=c>>6][d][e=c&63] (z<3) or Wo[d][c] (z==3), bf16
// ---------------------------------------------------------------------------
__global__ void prep_weights(const float* __restrict__ Wq, const float* __restrict__ Wk,
                             const float* __restrict__ Wv, const float* __restrict__ Wo,
                             unsigned short* __restrict__ dstBase) {
  const int z = blockIdx.z;
  const float* src = (z == 0) ? Wq : (z == 1) ? Wk : (z == 2) ? Wv : Wo;
  unsigned short* dst = dstBase + (size_t)z * (1024u * 1024u);
  const int idx = blockIdx.x * 256 + threadIdx.x;  // 131072 threads
  const int c = idx & 1023;
  const int d0 = (idx >> 10) << 3;
  unsigned short hv[8];
#pragma unroll
  for (int t = 0; t < 8; ++t) {
    const int d = d0 + t;
    const float v = (z < 3) ? src[(size_t)((c >> 6) * 1024 + d) * 64 + (c & 63)]
                            : src[(size_t)d * 1024 + c];
    hv[t] = f2bf(v);
  }
  *(uint4*)(dst + (size_t)c * 1024 + d0) = *(const uint4*)hv;
}

// ---------------------------------------------------------------------------
// QKV projection GEMM: C[4096x1024] = A(f32) * W^T(bf16), 128x128, BK=32.
// A tile staged as f32 (16KB/buf) via global_load_lds; converted to bf16 in
// the fragment read with v_cvt_pk_bf16_f32. 2-phase double buffer.
// Grid: 768 blocks 1-D, XCD-clustered decode (768 = 8 xcd x 4 x-local x 24 y).
// ---------------------------------------------------------------------------
__global__ __launch_bounds__(256, 3)
void proj_gemm(const float* __restrict__ Qm, const float* __restrict__ Tm,
               const float* __restrict__ Vm, const unsigned short* __restrict__ Wt,
               const float* __restrict__ bq, const float* __restrict__ bk,
               const float* __restrict__ bv, unsigned short* __restrict__ qb,
               unsigned short* __restrict__ kb, unsigned short* __restrict__ vtb) {
  __shared__ float Af[2][128 * 32];           // 32 KB
  __shared__ unsigned short Bt[2][128 * 32];  // 16 KB

  const int tid = threadIdx.x;
  const int lane = tid & 63;
  const int w = tid >> 6;
  const int g = lane >> 4, c = lane & 15;
  const int wm = w >> 1, wn = w & 1;

  const int orig = blockIdx.x;
  const int xcd = orig & 7;
  const int l = orig >> 3;          // 0..95
  const int bx = xcd * 4 + l / 24;  // 0..31
  const int by = l % 24;            // 0..23

  const int m0 = bx * 128;
  const int proj = by >> 3;
  const int n0 = (by & 7) * 128;

  const float* Asrc = (proj == 0) ? Qm : (proj == 1) ? Tm : Vm;
  const unsigned short* W = Wt + (size_t)proj * (1024u * 1024u);

  f32x4 acc[4][4];
#pragma unroll
  for (int i = 0; i < 4; ++i)
#pragma unroll
    for (int j = 0; j < 4; ++j) acc[i][j] = fzero();

  const int arow = w * 8 + (lane >> 3);  // A staging row within 32-row quarter
  const int ach = lane & 7;              // A 16B chunk (4 f32)
  const int brow = w * 16 + (lane >> 2); // B staging row within 64-row half
  const int bch = lane & 3;              // B 16B chunk (8 bf16)

  auto stage = [&](int kt, int buf) {
#pragma unroll
    for (int u = 0; u < 4; ++u) {  // A: 128 rows x 32 f32, 8 chunks/row
      const int row = u * 32 + arow;
      const int ch = ach ^ (row & 7);
      gld_lds16(Asrc + (size_t)(m0 + row) * 1024 + kt * 32 + ch * 4,
                &Af[buf][(u * 32 + w * 8) * 32]);
    }
#pragma unroll
    for (int u = 0; u < 2; ++u) {  // B: 128 rows x 32 bf16, 4 chunks/row
      const int row = u * 64 + brow;
      const int ch = bch ^ ((row >> 1) & 3);
      gld_lds16(W + (size_t)(n0 + row) * 1024 + kt * 32 + ch * 8,
                &Bt[buf][(u * 64 + w * 16) * 32]);
    }
  };

  stage(0, 0);
  __syncthreads();

  for (int kt = 0; kt < 32; ++kt) {
    const int buf = kt & 1;
    if (kt < 31) stage(kt + 1, buf ^ 1);

    bf16x8 af[4], bfr[4];
#pragma unroll
    for (int mi = 0; mi < 4; ++mi) {
      const int row = wm * 64 + mi * 16 + c;
      const int swz = row & 7;
      const float4 fa = *(const float4*)&Af[buf][row * 32 + ((2 * g) ^ swz) * 4];
      const float4 fb = *(const float4*)&Af[buf][row * 32 + ((2 * g + 1) ^ swz) * 4];
      U8 u8;
      asm("v_cvt_pk_bf16_f32 %0, %1, %2" : "=v"(u8.u[0]) : "v"(fa.x), "v"(fa.y));
      asm("v_cvt_pk_bf16_f32 %0, %1, %2" : "=v"(u8.u[1]) : "v"(fa.z), "v"(fa.w));
      asm("v_cvt_pk_bf16_f32 %0, %1, %2" : "=v"(u8.u[2]) : "v"(fb.x), "v"(fb.y));
      asm("v_cvt_pk_bf16_f32 %0, %1, %2" : "=v"(u8.u[3]) : "v"(fb.z), "v"(fb.w));
      af[mi] = u8.v;
    }
#pragma unroll
    for (int ni = 0; ni < 4; ++ni) {
      const int row = wn * 64 + ni * 16 + c;
      bfr[ni] = *(const bf16x8*)&Bt[buf][row * 32 + ((g ^ ((row >> 1) & 3))) * 8];
    }
#pragma unroll
    for (int mi = 0; mi < 4; ++mi)
#pragma unroll
      for (int ni = 0; ni < 4; ++ni)
        acc[mi][ni] = __builtin_amdgcn_mfma_f32_16x16x32_bf16(af[mi], bfr[ni],
                                                              acc[mi][ni], 0, 0, 0);
    __syncthreads();  // drains vmcnt: prefetched tile complete, cur tile free
  }

  const float* bias = (proj == 0) ? bq : (proj == 1) ? bk : bv;
  if (proj < 2) {
    unsigned short* dptr = (proj == 0) ? qb : kb;
#pragma unroll
    for (int ni = 0; ni < 4; ++ni) {
      const int colb = n0 + wn * 64 + ni * 16 + c;  // 0..1023 = h*64+e
      const float bc = bias[colb];
      const int hh = colb >> 6, e = colb & 63;
#pragma unroll
      for (int mi = 0; mi < 4; ++mi)
#pragma unroll
        for (int r = 0; r < 4; ++r) {
          const int row = m0 + wm * 64 + mi * 16 + g * 4 + r;  // b*S+s
          const int bb = row >> 11, s = row & 2047;
          dptr[(((size_t)(bb * H_ + hh)) * S_ + s) * 64 + e] = f2bf(acc[mi][ni][r] + bc);
        }
    }
  } else {  // v stored transposed per head [B,H,E,S]; 4 s-values pack to b64
#pragma unroll
    for (int ni = 0; ni < 4; ++ni) {
      const int colb = n0 + wn * 64 + ni * 16 + c;
      const float bc = bias[colb];
      const int hh = colb >> 6, e = colb & 63;
#pragma unroll
      for (int mi = 0; mi < 4; ++mi) {
        const int rowb = m0 + wm * 64 + mi * 16 + g * 4;  // 4-aligned, no b-cross
        const int bb = rowb >> 11, s0 = rowb & 2047;
        const float v0 = acc[mi][ni][0] + bc, v1 = acc[mi][ni][1] + bc;
        const float v2 = acc[mi][ni][2] + bc, v3 = acc[mi][ni][3] + bc;
        uint2 pk;
        asm("v_cvt_pk_bf16_f32 %0, %1, %2" : "=v"(pk.x) : "v"(v0), "v"(v1));
        asm("v_cvt_pk_bf16_f32 %0, %1, %2" : "=v"(pk.y) : "v"(v2), "v"(v3));
        *(uint2*)&vtb[(((size_t)(bb * H_ + hh)) * 64 + e) * S_ + s0] = pk;
      }
    }
  }
}

// ---------------------------------------------------------------------------
// Flash attention v9: KVBLK=128 per barrier. 512 blocks (XCD-swizzled),
// 4 waves x 32 q. K tile [128 kv][64 E] dbuf (32 KB); V^T tile [64 e][128 kv]
// dbuf (32 KB, chunk^(e&15) swizzle); Pt 16 KB -> 80 KB total (2 blocks/CU,
// grid-matched). Two 64-kv sub-tiles computed per staged tile with the
// round-8-verified inner math; ONE __syncthreads per 128 kv (16 barriers).
// ---------------------------------------------------------------------------
__global__ __launch_bounds__(256, 2)
void attn_kernel(const unsigned short* __restrict__ qb,
                 const unsigned short* __restrict__ kb,
                 const unsigned short* __restrict__ vtb,
                 unsigned short* __restrict__ att) {
  __shared__ unsigned short Kt[2][128 * 64];  // 32 KB
  __shared__ unsigned short Vt[2][64 * 128];  // 32 KB
  __shared__ unsigned short Pt[4][32 * 64];   // 16 KB

  const int tid = threadIdx.x;
  const int lane = tid & 63;
  const int w = tid >> 6;
  const int g = lane >> 4, c = lane & 15;

  const int orig = blockIdx.x;                    // 0..511
  const int logical = ((orig & 7) << 6) | (orig >> 3);
  const int qblk = logical & 15;                  // 16 q-blocks of 128 rows
  const int bh = logical >> 4;                    // b*16+h, 0..31
  const int hh = bh & 15, bz = bh >> 4;

  const int q0w = qblk * 128 + w * 32;            // wave's 32 q rows
  const unsigned short* qh = qb + (size_t)bh * S_ * 64;
  const unsigned short* kh = kb + (size_t)bh * S_ * 64;
  const unsigned short* vh = vtb + (size_t)bh * 64 * S_;

  bf16x8 aq[2][2];
#pragma unroll
  for (int m = 0; m < 2; ++m)
#pragma unroll
    for (int t = 0; t < 2; ++t)
      aq[m][t] = *(const bf16x8*)&qh[(size_t)(q0w + m * 16 + c) * 64 + t * 32 + g * 8];

  bf16x8 onesB;
#pragma unroll
  for (int i = 0; i < 8; ++i) onesB[i] = (short)0x3F80;

  f32x4 O[2][4];
  f32x4 accL[2];
#pragma unroll
  for (int m = 0; m < 2; ++m) {
#pragma unroll
    for (int ne = 0; ne < 4; ++ne) O[m][ne] = fzero();
    accL[m] = fzero();
  }

  constexpr float L2E = 1.4426950408889634f;
  const float S2 = 0.125f * L2E;
  const float B2 = 0.125f * L2E;

  // ---- loop-invariant LDS byte offsets ----
  int kaOff[2][4];     // K read [ks][mi]; sub s adds s*8192 bytes
  int vOff[2][2][4];   // V read [sub][ks][ne]
  int paOff[2][2], pwOff[2][4];
#pragma unroll
  for (int ks = 0; ks < 2; ++ks) {
#pragma unroll
    for (int mi = 0; mi < 4; ++mi) {
      const int row = mi * 16 + c;
      kaOff[ks][mi] = 2 * (row * 64 + ((ks * 4 + g) ^ (row & 7)) * 8);
    }
#pragma unroll
    for (int m = 0; m < 2; ++m)
      paOff[m][ks] = 2 * ((m * 16 + c) * 64 + ((ks * 4 + g) ^ (c & 7)) * 8);
  }
#pragma unroll
  for (int s = 0; s < 2; ++s)
#pragma unroll
    for (int ks = 0; ks < 2; ++ks)
#pragma unroll
      for (int ne = 0; ne < 4; ++ne) {
        const int e = ne * 16 + c;  // e&15 == c
        vOff[s][ks][ne] = 2 * (e * 128 + ((s * 8 + ks * 4 + g) ^ c) * 8);
      }
#pragma unroll
  for (int m = 0; m < 2; ++m)
#pragma unroll
    for (int mi = 0; mi < 4; ++mi)
      pwOff[m][mi] =
          2 * ((m * 16 + c) * 64 + ((2 * mi + (g >> 1)) ^ (c & 7)) * 8 + (g & 1) * 4);

  // ---- staging source pointers ----
  const int srowK = w * 8 + (lane >> 3);
  const int schK = (lane & 7) ^ (srowK & 7);
  const unsigned short* kS = kh + (size_t)srowK * 64 + schK * 8;
  const int rowV = w * 4 + (lane >> 4);           // e&15 for this lane's rows
  const int jV = (lane & 15) ^ rowV;
  const unsigned short* vS = vh + (size_t)rowV * S_ + jV * 8;

  {  // prologue: stage tile 0 (128 kv) into buffer 0
#pragma unroll
    for (int u = 0; u < 4; ++u) {
      gld_lds16(kS + u * 2048, &Kt[0][(u * 32 + w * 8) * 64]);
      gld_lds16(vS + (size_t)u * 32768, &Vt[0][(u * 16 + w * 4) * 128]);
    }
  }
  __syncthreads();

// one 64-kv sub-tile: QK -> softmax -> P -> PV (round-8 verified math)
#define ATTN_SUB(J0S, SB, CUR)                                                 \
  do {                                                                         \
    const int j0 = (J0S);                                                      \
    f32x4 sa[2][4];                                                            \
    _Pragma("unroll")                                                          \
    for (int m = 0; m < 2; ++m)                                                \
      _Pragma("unroll")                                                        \
      for (int mi = 0; mi < 4; ++mi) sa[m][mi] = fzero();                      \
    __builtin_amdgcn_s_setprio(1);                                             \
    _Pragma("unroll")                                                          \
    for (int ks = 0; ks < 2; ++ks)                                             \
      _Pragma("unroll")                                                        \
      for (int mi = 0; mi < 4; ++mi) {                                         \
        const bf16x8 ka = *(const bf16x8*)((const char*)&Kt[CUR][0] +          \
                                           (SB) * 8192 + kaOff[ks][mi]);       \
        sa[0][mi] = __builtin_amdgcn_mfma_f32_16x16x32_bf16(ka, aq[0][ks],     \
                                                            sa[0][mi], 0, 0, 0);\
        sa[1][mi] = __builtin_amdgcn_mfma_f32_16x16x32_bf16(ka, aq[1][ks],     \
                                                            sa[1][mi], 0, 0, 0);\
      }                                                                        \
    __builtin_amdgcn_s_setprio(0);                                             \
    const bool allUp = (j0 >= q0w + 32);                                       \
    const bool noneUp = (j0 + 63 <= q0w);                                      \
    _Pragma("unroll")                                                          \
    for (int m = 0; m < 2; ++m) {                                              \
      const int iq = q0w + m * 16 + c;                                         \
      _Pragma("unroll")                                                        \
      for (int mi = 0; mi < 4; ++mi) {                                         \
        float pv[4];                                                           \
        if (allUp || noneUp) {                                                 \
          const float bb = allUp ? B2 : 0.f;                                   \
          _Pragma("unroll")                                                    \
          for (int r = 0; r < 4; ++r) {                                        \
            const float v = sa[m][mi][r];                                      \
            pv[r] = __builtin_amdgcn_exp2f(                                    \
                (v > 0.1f) ? __builtin_fmaf(v, S2, bb) : bb);                  \
          }                                                                    \
        } else {                                                               \
          _Pragma("unroll")                                                    \
          for (int r = 0; r < 4; ++r) {                                        \
            const float v = sa[m][mi][r];                                      \
            const float bb = (j0 + mi * 16 + g * 4 + r > iq) ? B2 : 0.f;       \
            pv[r] = __builtin_amdgcn_exp2f(                                    \
                (v > 0.1f) ? __builtin_fmaf(v, S2, bb) : bb);                  \
          }                                                                    \
        }                                                                      \
        uint2 d;                                                               \
        asm("v_cvt_pk_bf16_f32 %0, %1, %2"                                     \
            : "=v"(d.x) : "v"(pv[0]), "v"(pv[1]));                             \
        asm("v_cvt_pk_bf16_f32 %0, %1, %2"                                     \
            : "=v"(d.y) : "v"(pv[2]), "v"(pv[3]));                             \
        *(uint2*)((char*)&Pt[w][0] + pwOff[m][mi]) = d;                        \
      }                                                                        \
    }                                                                          \
    asm volatile("s_waitcnt lgkmcnt(0)" ::: "memory");                         \
    __builtin_amdgcn_sched_barrier(0);                                         \
    __builtin_amdgcn_s_setprio(1);                                             \
    _Pragma("unroll")                                                          \
    for (int ks = 0; ks < 2; ++ks) {                                           \
      const bf16x8 pa0 =                                                       \
          *(const bf16x8*)((const char*)&Pt[w][0] + paOff[0][ks]);             \
      const bf16x8 pa1 =                                                       \
          *(const bf16x8*)((const char*)&Pt[w][0] + paOff[1][ks]);             \
      accL[0] = __builtin_amdgcn_mfma_f32_16x16x32_bf16(pa0, onesB, accL[0],   \
                                                        0, 0, 0);              \
      accL[1] = __builtin_amdgcn_mfma_f32_16x16x32_bf16(pa1, onesB, accL[1],   \
                                                        0, 0, 0);              \
      _Pragma("unroll")                                                        \
      for (int ne = 0; ne < 4; ++ne) {                                         \
        const bf16x8 bv8 = *(const bf16x8*)((const char*)&Vt[CUR][0] +         \
                                            vOff[SB][ks][ne]);                 \
        O[0][ne] = __builtin_amdgcn_mfma_f32_16x16x32_bf16(pa0, bv8, O[0][ne], \
                                                           0, 0, 0);           \
        O[1][ne] = __builtin_amdgcn_mfma_f32_16x16x32_bf16(pa1, bv8, O[1][ne], \
                                                           0, 0, 0);           \
      }                                                                        \
    }                                                                          \
    __builtin_amdgcn_s_setprio(0);                                             \
  } while (0)

#define ATTN_TILE(T, CUR)                                                      \
  do {                                                                         \
    if ((T) < 15) { /* prefetch next 128-kv tile into the other buffer */      \
      _Pragma("unroll")                                                        \
      for (int u = 0; u < 4; ++u) {                                            \
        gld_lds16(kS + 8192 + u * 2048, &Kt[CUR ^ 1][(u * 32 + w * 8) * 64]);  \
        gld_lds16(vS + 128 + (size_t)u * 32768,                                \
                  &Vt[CUR ^ 1][(u * 16 + w * 4) * 128]);                       \
      }                                                                        \
      kS += 8192; vS += 128;                                                   \
    }                                                                          \
    ATTN_SUB((T) * 128, 0, CUR);                                               \
    ATTN_SUB((T) * 128 + 64, 1, CUR);                                          \
    __syncthreads(); /* drains prefetch; releases cur for next stage */        \
  } while (0)

  for (int T = 0; T < 16; T += 2) {
    ATTN_TILE(T, 0);
    ATTN_TILE(T + 1, 1);
  }
#undef ATTN_TILE
#undef ATTN_SUB

  // epilogue: il = 1/accL (accL rows == O rows); store concat [B,S,H*E] bf16
#pragma unroll
  for (int m = 0; m < 2; ++m)
#pragma unroll
    for (int r = 0; r < 4; ++r) {
      const float il = 1.f / accL[m][r];
      const int qg = q0w + m * 16 + g * 4 + r;
      const size_t ro = ((size_t)(bz * S_ + qg)) * 1024 + hh * 64;
#pragma unroll
      for (int ne = 0; ne < 4; ++ne)
        att[ro + ne * 16 + c] = f2bf(O[m][ne][r] * il);
    }
}

// ---------------------------------------------------------------------------
// Output projection: out[4096x1024] = att(bf16) @ Wo + bo, -> f32 d_out.
// Grid: 256 blocks 1-D, XCD-clustered (256 = 8 xcd x 4 x-local x 8 y).
// ---------------------------------------------------------------------------
__global__ __launch_bounds__(256, 3)
void out_gemm(const unsigned short* __restrict__ att,
              const unsigned short* __restrict__ WoT,
              const float* __restrict__ bo, float* __restrict__ outp) {
  __shared__ unsigned short At[2][128 * 32];
  __shared__ unsigned short Bt[2][128 * 32];

  const int tid = threadIdx.x;
  const int lane = tid & 63;
  const int w = tid >> 6;
  const int g = lane >> 4, c = lane & 15;
  const int wm = w >> 1, wn = w & 1;

  const int orig = blockIdx.x;
  const int xcd = orig & 7;
  const int l = orig >> 3;          // 0..31
  const int bx = xcd * 4 + l / 8;   // 0..31
  const int by = l % 8;             // 0..7
  const int m0 = bx * 128;
  const int n0 = by * 128;

  f32x4 acc[4][4];
#pragma unroll
  for (int i = 0; i < 4; ++i)
#pragma unroll
    for (int j = 0; j < 4; ++j) acc[i][j] = fzero();

  const int srow = lane >> 2;
  const int sch = lane & 3;

  auto stage = [&](int kt, int buf) {
#pragma unroll
    for (int u = 0; u < 2; ++u) {
      const int row = u * 64 + w * 16 + srow;
      const int ch = sch ^ ((row >> 1) & 3);
      gld_lds16(att + (size_t)(m0 + row) * 1024 + kt * 32 + ch * 8,
                &At[buf][(u * 64 + w * 16) * 32]);
      gld_lds16(WoT + (size_t)(n0 + row) * 1024 + kt * 32 + ch * 8,
                &Bt[buf][(u * 64 + w * 16) * 32]);
    }
  };

  stage(0, 0);
  __syncthreads();

  for (int kt = 0; kt < 32; ++kt) {
    const int buf = kt & 1;
    if (kt < 31) stage(kt + 1, buf ^ 1);

    bf16x8 af[4], bfr[4];
#pragma unroll
    for (int mi = 0; mi < 4; ++mi) {
      const int row = wm * 64 + mi * 16 + c;
      af[mi] = *(const bf16x8*)&At[buf][row * 32 + ((g ^ ((row >> 1) & 3))) * 8];
    }
#pragma unroll
    for (int ni = 0; ni < 4; ++ni) {
      const int row = wn * 64 + ni * 16 + c;
      bfr[ni] = *(const bf16x8*)&Bt[buf][row * 32 + ((g ^ ((row >> 1) & 3))) * 8];
    }
#pragma unroll
    for (int mi = 0; mi < 4; ++mi)
#pragma unroll
      for (int ni = 0; ni < 4; ++ni)
        acc[mi][ni] = __builtin_amdgcn_mfma_f32_16x16x32_bf16(af[mi], bfr[ni],
                                                              acc[mi][ni], 0, 0, 0);
    __syncthreads();
  }

#pragma unroll
  for (int ni = 0; ni < 4; ++ni) {
    const int colb = n0 + wn * 64 + ni * 16 + c;
    const float bc = bo[colb];
#pragma unroll
    for (int mi = 0; mi < 4; ++mi)
#pragma unroll
      for (int r = 0; r < 4; ++r) {
        const int row = m0 + wm * 64 + mi * 16 + g * 4 + r;
        outp[(size_t)row * 1024 + colb] = acc[mi][ni][r] + bc;
      }
  }
}

// ---------------------------------------------------------------------------
extern "C" void kernel_launch(void* const* d_in, const int* in_sizes, int n_in,
                              void* d_out, int out_size, void* d_ws, size_t ws_size,
                              hipStream_t stream) {
  const float* Q  = (const float*)d_in[0];
  const float* T  = (const float*)d_in[1];
  const float* V  = (const float*)d_in[2];
  const float* Wq = (const float*)d_in[3];
  const float* bq = (const float*)d_in[4];
  const float* Wk = (const float*)d_in[5];
  const float* bk = (const float*)d_in[6];
  const float* Wv = (const float*)d_in[7];
  const float* bv = (const float*)d_in[8];
  const float* Wo = (const float*)d_in[9];
  const float* bo = (const float*)d_in[10];

  const size_t MB = 1024ull * 1024ull;
  if (ws_size < 40 * MB) return;  // need 40 MB scratch; clean fail otherwise

  uint8_t* ws = (uint8_t*)d_ws;
  unsigned short* Wt  = (unsigned short*)(ws);            // 8MB: WqT,WkT,WvT,WoT
  unsigned short* qb  = (unsigned short*)(ws + 8 * MB);   // 8MB  [B,H,S,E]
  unsigned short* kb  = (unsigned short*)(ws + 16 * MB);  // 8MB  [B,H,S,E]
  unsigned short* vtb = (unsigned short*)(ws + 24 * MB);  // 8MB  [B,H,E,S]
  unsigned short* attb = (unsigned short*)(ws + 32 * MB); // 8MB  [B,S,H*E]

  prep_weights<<<dim3(512, 1, 4), 256, 0, stream>>>(Wq, Wk, Wv, Wo, Wt);
  proj_gemm<<<dim3(768), 256, 0, stream>>>(Q, T, V, Wt, bq, bk, bv,
                                           qb, kb, vtb);
  attn_kernel<<<dim3(512), 256, 0, stream>>>(qb, kb, vtb, attb);
  out_gemm<<<dim3(256), 256, 0, stream>>>(attb, Wt + 3ull * 1024ull * 1024ull,
                                          bo, (float*)d_out);
}